// Round 2
// baseline (2526.272 us; speedup 1.0000x reference)
//
#include <hip/hip_runtime.h>

typedef unsigned short ushortT;
typedef short bf16x8 __attribute__((ext_vector_type(8)));   // 8 bf16 in 4 VGPRs
typedef float f32x4 __attribute__((ext_vector_type(4)));

#define NDIM 2048
#define NTOT (2048 * 2048)
#define N4 (NTOT / 4)

__device__ __forceinline__ ushortT f2bf(float f) {
    unsigned u = __float_as_uint(f);
    u += 0x7fffu + ((u >> 16) & 1u);   // RNE; inputs finite
    return (ushortT)(u >> 16);
}
__device__ __forceinline__ float tanh_fast(float x) {
    // tanh(x) = 1 - 2/(e^{2x}+1); exact saturation at +/-inf via __expf
    float e = __expf(2.0f * x);
    return 1.0f - 2.0f / (e + 1.0f);
}
__device__ __forceinline__ void gload_lds16(const void* g, void* l) {
    __builtin_amdgcn_global_load_lds(
        (const __attribute__((address_space(1))) void*)g,
        (__attribute__((address_space(3))) void*)l, 16, 0, 0);
}
__device__ __forceinline__ unsigned hash_u32(unsigned x) {
    x ^= x >> 16; x *= 0x7feb352du; x ^= x >> 15; x *= 0x846ca68bu; x ^= x >> 16;
    return x;
}

// ---------------- transpose + cast: W (f32 row-major [k][n]) -> WT bf16 [n][k]
__global__ void k_transpose(const float* __restrict__ W, ushortT* __restrict__ WT) {
    __shared__ float tile[32][33];
    const int bx = blockIdx.x * 32, by = blockIdx.y * 32;
    const int tx = threadIdx.x, ty = threadIdx.y;  // (32,8)
#pragma unroll
    for (int r = 0; r < 32; r += 8)
        tile[ty + r][tx] = W[(size_t)(by + ty + r) * NDIM + bx + tx];
    __syncthreads();
#pragma unroll
    for (int r = 0; r < 32; r += 8)
        WT[(size_t)(bx + ty + r) * NDIM + by + tx] = f2bf(tile[tx][ty + r]);
}

// ---------------- init: F0 = tanh(u), X0 = 0, X1 = F0, Abf = bf16(F0); zero dots
__global__ void k_init(const float* __restrict__ U, float* __restrict__ X0,
                       float* __restrict__ X1, float* __restrict__ F0,
                       ushortT* __restrict__ Abf, float* __restrict__ dots) {
    const int stride = gridDim.x * blockDim.x;
    for (int i = blockIdx.x * blockDim.x + threadIdx.x; i < N4; i += stride) {
        float4 u = ((const float4*)U)[i];
        float4 t;
        t.x = tanh_fast(u.x); t.y = tanh_fast(u.y);
        t.z = tanh_fast(u.z); t.w = tanh_fast(u.w);
        ((float4*)F0)[i] = t;
        ((float4*)X1)[i] = t;
        ((float4*)X0)[i] = make_float4(0.f, 0.f, 0.f, 0.f);
        ushort4 p; p.x = f2bf(t.x); p.y = f2bf(t.y); p.z = f2bf(t.z); p.w = f2bf(t.w);
        ((ushort4*)Abf)[i] = p;
    }
    if (blockIdx.x == 0 && threadIdx.x == 0)
        for (int i = 0; i < 32; ++i) dots[i] = 0.f;
}

// ---------------- GEMM: C = A(bf16) @ Bt(bf16)^T ; MODE 0: out = tanh(C + U)
//                  MODE 1: jac += sum(((1-xstar^2)*C)^2)/NTOT   (A = eps)
template <int MODE>
__global__ __launch_bounds__(256) void k_gemm(
    const ushortT* __restrict__ A, const ushortT* __restrict__ Bt,
    const float* __restrict__ U, float* __restrict__ out,
    const float* __restrict__ xstar, float* __restrict__ jac) {
    __shared__ __align__(16) ushortT lA[2][128 * 32];
    __shared__ __align__(16) ushortT lB[2][128 * 32];
    const int tid = threadIdx.x;
    const int bm = blockIdx.y, bn = blockIdx.x;

    f32x4 acc[4][4] = {};

    const int w = tid >> 6, lane = tid & 63;
    const int wm = (w >> 1) * 64, wn = (w & 1) * 64;
    const int lr = lane & 15, lk = (lane >> 4) * 8;

#define STAGE(buf, kt) do {                                                              \
        const int k0s = (kt) * 32;                                                       \
        { const int idx = tid;                                                           \
          gload_lds16(A  + (size_t)(bm * 128 + (idx >> 2)) * NDIM + k0s + ((idx & 3) << 3), &lA[buf][idx * 8]); \
          gload_lds16(Bt + (size_t)(bn * 128 + (idx >> 2)) * NDIM + k0s + ((idx & 3) << 3), &lB[buf][idx * 8]); } \
        { const int idx = 256 + tid;                                                     \
          gload_lds16(A  + (size_t)(bm * 128 + (idx >> 2)) * NDIM + k0s + ((idx & 3) << 3), &lA[buf][idx * 8]); \
          gload_lds16(Bt + (size_t)(bn * 128 + (idx >> 2)) * NDIM + k0s + ((idx & 3) << 3), &lB[buf][idx * 8]); } \
    } while (0)

    STAGE(0, 0);
    int cur = 0;
    for (int kt = 0; kt < 64; ++kt) {
        __syncthreads();                    // drains staged loads (compiler vmcnt) + buffer reuse
        if (kt + 1 < 64) STAGE(cur ^ 1, kt + 1);
        bf16x8 af[4], bfr[4];
#pragma unroll
        for (int m = 0; m < 4; ++m)
            af[m] = *(const bf16x8*)&lA[cur][(wm + m * 16 + lr) * 32 + lk];
#pragma unroll
        for (int n = 0; n < 4; ++n)
            bfr[n] = *(const bf16x8*)&lB[cur][(wn + n * 16 + lr) * 32 + lk];
#pragma unroll
        for (int m = 0; m < 4; ++m)
#pragma unroll
            for (int n = 0; n < 4; ++n)
                acc[m][n] = __builtin_amdgcn_mfma_f32_16x16x32_bf16(af[m], bfr[n], acc[m][n], 0, 0, 0);
        cur ^= 1;
    }
#undef STAGE

    const int r0 = (lane >> 4) * 4;   // C/D: col = lane&15, row = (lane>>4)*4 + reg
    if (MODE == 0) {
#pragma unroll
        for (int m = 0; m < 4; ++m) {
            const int row = bm * 128 + wm + m * 16 + r0;
#pragma unroll
            for (int n = 0; n < 4; ++n) {
                const int col = bn * 128 + wn + n * 16 + lr;
#pragma unroll
                for (int r = 0; r < 4; ++r) {
                    const size_t o = (size_t)(row + r) * NDIM + col;
                    out[o] = tanh_fast(acc[m][n][r] + U[o]);
                }
            }
        }
    } else {
        float psum = 0.f;
#pragma unroll
        for (int m = 0; m < 4; ++m) {
            const int row = bm * 128 + wm + m * 16 + r0;
#pragma unroll
            for (int n = 0; n < 4; ++n) {
                const int col = bn * 128 + wn + n * 16 + lr;
#pragma unroll
                for (int r = 0; r < 4; ++r) {
                    const size_t o = (size_t)(row + r) * NDIM + col;
                    const float t = xstar[o];
                    const float tang = (1.f - t * t) * acc[m][n][r];
                    psum += tang * tang;
                }
            }
        }
#pragma unroll
        for (int off = 32; off > 0; off >>= 1) psum += __shfl_down(psum, off);
        __shared__ float red[4];
        if (lane == 0) red[w] = psum;
        __syncthreads();
        if (tid == 0)
            atomicAdd(jac, (red[0] + red[1] + red[2] + red[3]) * (1.0f / (float)NTOT));
    }
}

// ---------------- Anderson 5x5 solve (1 thread, fp64); zeroes row/col s for re-accumulation
__global__ void k_solve(float* dots, float* alpha, int nk, int s) {
    if (threadIdx.x != 0) return;
    double H[5][5], rhs[5], x[5];
    for (int i = 0; i < nk; ++i) {
        for (int j = 0; j < nk; ++j)
            H[i][j] = (double)dots[i * 5 + j] + (i == j ? 1e-4 : 0.0);
        rhs[i] = 1.0;
    }
    for (int c = 0; c < nk; ++c) {
        int p = c; double mx = fabs(H[c][c]);
        for (int r = c + 1; r < nk; ++r) { double a = fabs(H[r][c]); if (a > mx) { mx = a; p = r; } }
        if (p != c) {
            for (int j = 0; j < nk; ++j) { double tv = H[c][j]; H[c][j] = H[p][j]; H[p][j] = tv; }
            double tr = rhs[c]; rhs[c] = rhs[p]; rhs[p] = tr;
        }
        double d = H[c][c]; if (fabs(d) < 1e-300) d = 1e-300;
        for (int r = c + 1; r < nk; ++r) {
            double f = H[r][c] / d;
            for (int j = c; j < nk; ++j) H[r][j] -= f * H[c][j];
            rhs[r] -= f * rhs[c];
        }
    }
    for (int c = nk - 1; c >= 0; --c) {
        double v = rhs[c];
        for (int j = c + 1; j < nk; ++j) v -= H[c][j] * x[j];
        double d = H[c][c]; if (fabs(d) < 1e-300) d = 1e-300;
        x[c] = v / d;
    }
    double sum = 0.0;
    for (int i = 0; i < nk; ++i) sum += x[i];
    if (sum == 0.0) sum = 1.0;
    for (int i = 0; i < 5; ++i) alpha[i] = (i < nk) ? (float)(x[i] / sum) : 0.f;
    for (int j = 0; j < 5; ++j) { dots[s * 5 + j] = 0.f; dots[j * 5 + s] = 0.f; }
}

// ---------------- mix: xk = sum alpha_i F_i -> X[s] (f32) and Abf (bf16)
__global__ void k_mix(const float* __restrict__ F, const float* __restrict__ alpha,
                      float* __restrict__ Xout, ushortT* __restrict__ Abf, int nk) {
    float a[5];
#pragma unroll
    for (int i = 0; i < 5; ++i) a[i] = alpha[i];
    const int stride = gridDim.x * blockDim.x;
    for (int i = blockIdx.x * blockDim.x + threadIdx.x; i < N4; i += stride) {
        float4 sv = make_float4(0.f, 0.f, 0.f, 0.f);
#pragma unroll
        for (int j = 0; j < 5; ++j)
            if (j < nk) {
                float4 f = ((const float4*)(F + (size_t)j * NTOT))[i];
                sv.x += a[j] * f.x; sv.y += a[j] * f.y;
                sv.z += a[j] * f.z; sv.w += a[j] * f.w;
            }
        ((float4*)Xout)[i] = sv;
        ushort4 p; p.x = f2bf(sv.x); p.y = f2bf(sv.y); p.z = f2bf(sv.z); p.w = f2bf(sv.w);
        ((ushort4*)Abf)[i] = p;
    }
}

// ---------------- dots: row s of H-gram: <g_s, g_i> for i < cnt (g = F - X)
__global__ void k_dots(const float* __restrict__ F, const float* __restrict__ X,
                       float* dots, int s, int cnt) {
    float d[5] = {0.f, 0.f, 0.f, 0.f, 0.f};
    const int stride = gridDim.x * blockDim.x;
    const float4* F4 = (const float4*)F;
    const float4* X4 = (const float4*)X;
    const size_t s4 = (size_t)s * N4;
    for (int i = blockIdx.x * blockDim.x + threadIdx.x; i < N4; i += stride) {
        float4 fs = F4[s4 + i], xs = X4[s4 + i];
        float4 gs = make_float4(fs.x - xs.x, fs.y - xs.y, fs.z - xs.z, fs.w - xs.w);
#pragma unroll
        for (int j = 0; j < 5; ++j)
            if (j < cnt) {
                float4 fj = F4[(size_t)j * N4 + i], xj = X4[(size_t)j * N4 + i];
                d[j] += gs.x * (fj.x - xj.x) + gs.y * (fj.y - xj.y) +
                        gs.z * (fj.z - xj.z) + gs.w * (fj.w - xj.w);
            }
    }
    const int w = threadIdx.x >> 6, lane = threadIdx.x & 63;
    __shared__ float red[4][5];
#pragma unroll
    for (int j = 0; j < 5; ++j) {
        float v = d[j];
#pragma unroll
        for (int off = 32; off > 0; off >>= 1) v += __shfl_down(v, off);
        if (lane == 0) red[w][j] = v;
    }
    __syncthreads();
    if (threadIdx.x < 5) {
        const int j = threadIdx.x;
        if (j < cnt) {
            const float v = red[0][j] + red[1][j] + red[2][j] + red[3][j];
            atomicAdd(&dots[s * 5 + j], v);
            if (j != s) atomicAdd(&dots[j * 5 + s], v);
        }
    }
}

// ---------------- eps: Rademacher +/-1 in bf16
__global__ void k_eps(ushortT* __restrict__ E) {
    const int stride = gridDim.x * blockDim.x;
    for (int i = blockIdx.x * blockDim.x + threadIdx.x; i < N4; i += stride) {
        ushort4 p;
        p.x = (hash_u32(4u * i + 0u) & 1u) ? 0xBF80u : 0x3F80u;
        p.y = (hash_u32(4u * i + 1u) & 1u) ? 0xBF80u : 0x3F80u;
        p.z = (hash_u32(4u * i + 2u) & 1u) ? 0xBF80u : 0x3F80u;
        p.w = (hash_u32(4u * i + 3u) & 1u) ? 0xBF80u : 0x3F80u;
        ((ushort4*)E)[i] = p;
    }
}

extern "C" void kernel_launch(void* const* d_in, const int* in_sizes, int n_in,
                              void* d_out, int out_size, void* d_ws, size_t ws_size,
                              hipStream_t stream) {
    const float* W = (const float*)d_in[1];   // d_in[0] = x is unused (x0 = zeros)
    const float* U = (const float*)d_in[2];
    float* out = (float*)d_out;

    // ws layout: WT bf16 (8MB) | Abf bf16 (8MB, reused as eps) | F[5] f32 (80MB) | X[5] f32 (80MB) | dots(32) | alpha(8)
    ushortT* WT  = (ushortT*)d_ws;
    ushortT* Abf = WT + (size_t)NTOT;
    float* Fs    = (float*)(Abf + (size_t)NTOT);
    float* Xs    = Fs + (size_t)5 * NTOT;
    float* dots  = Xs + (size_t)5 * NTOT;
    float* alpha = dots + 32;

    hipMemsetAsync(out + NTOT, 0, sizeof(float), stream);   // jac accumulator

    k_transpose<<<dim3(64, 64), dim3(32, 8), 0, stream>>>(W, WT);
    k_init<<<1024, 256, 0, stream>>>(U, Xs, Xs + NTOT, Fs, Abf, dots);
    // F1 = tanh(F0 @ W + u)
    k_gemm<0><<<dim3(16, 16), 256, 0, stream>>>(Abf, WT, U, Fs + NTOT, nullptr, nullptr);
    k_dots<<<1024, 256, 0, stream>>>(Fs, Xs, dots, 0, 1);
    k_dots<<<1024, 256, 0, stream>>>(Fs, Xs, dots, 1, 2);

    for (int k = 2; k < 20; ++k) {
        const int s = k % 5;
        const int nk = k < 5 ? k : 5;
        k_solve<<<1, 64, 0, stream>>>(dots, alpha, nk, s);
        k_mix<<<1024, 256, 0, stream>>>(Fs, alpha, Xs + (size_t)s * NTOT, Abf, nk);
        float* Fout = (k == 19) ? out : (Fs + (size_t)s * NTOT);
        k_gemm<0><<<dim3(16, 16), 256, 0, stream>>>(Abf, WT, U, Fout, nullptr, nullptr);
        if (k < 19) {
            const int cnt = (k + 1 < 5) ? (k + 1) : 5;
            k_dots<<<1024, 256, 0, stream>>>(Fs, Xs, dots, s, cnt);
        }
    }
    // jac_reg: Hutchinson probe with independent Rademacher eps (estimator std ~3e-4 << 2e-2)
    k_eps<<<1024, 256, 0, stream>>>(Abf);
    k_gemm<1><<<dim3(16, 16), 256, 0, stream>>>(Abf, WT, nullptr, nullptr, out, out + NTOT);
}

// Round 4
// 2422.041 us; speedup vs baseline: 1.0430x; 1.0430x over previous
//
#include <hip/hip_runtime.h>

typedef unsigned short ushortT;
typedef short bf16x8 __attribute__((ext_vector_type(8)));   // 8 bf16 in 4 VGPRs
typedef float f32x4 __attribute__((ext_vector_type(4)));

#define NDIM 2048
#define NTOT (2048 * 2048)
#define N4 (NTOT / 4)
#define BK 64          // K-tile depth
#define GEMM_GRID dim3(32, 16)   // bn x bm : 128x64 tiles -> 512 blocks (2/CU)

__device__ __forceinline__ ushortT f2bf(float f) {
    unsigned u = __float_as_uint(f);
    u += 0x7fffu + ((u >> 16) & 1u);   // RNE; inputs finite
    return (ushortT)(u >> 16);
}
__device__ __forceinline__ float tanh_fast(float x) {
    float e = __expf(2.0f * x);
    return 1.0f - 2.0f / (e + 1.0f);
}
__device__ __forceinline__ void gload_lds16(const void* g, void* l) {
    __builtin_amdgcn_global_load_lds(
        (const __attribute__((address_space(1))) void*)g,
        (__attribute__((address_space(3))) void*)l, 16, 0, 0);
}
__device__ __forceinline__ unsigned hash_u32(unsigned x) {
    x ^= x >> 16; x *= 0x7feb352du; x ^= x >> 15; x *= 0x846ca68bu; x ^= x >> 16;
    return x;
}

// 5x5 ridge-normal-equation solve (LU w/ pivoting, fp64), alpha normalized.
__device__ void solve5(const float* dots, float* alphaOut, int nk) {
    double H[5][5], rhs[5], x[5];
    for (int i = 0; i < nk; ++i) {
        for (int j = 0; j < nk; ++j)
            H[i][j] = (double)dots[i * 5 + j] + (i == j ? 1e-4 : 0.0);
        rhs[i] = 1.0;
    }
    for (int c = 0; c < nk; ++c) {
        int p = c; double mx = fabs(H[c][c]);
        for (int r = c + 1; r < nk; ++r) { double a = fabs(H[r][c]); if (a > mx) { mx = a; p = r; } }
        if (p != c) {
            for (int j = 0; j < nk; ++j) { double tv = H[c][j]; H[c][j] = H[p][j]; H[p][j] = tv; }
            double tr = rhs[c]; rhs[c] = rhs[p]; rhs[p] = tr;
        }
        double d = H[c][c]; if (fabs(d) < 1e-300) d = 1e-300;
        for (int r = c + 1; r < nk; ++r) {
            double f = H[r][c] / d;
            for (int j = c; j < nk; ++j) H[r][j] -= f * H[c][j];
            rhs[r] -= f * rhs[c];
        }
    }
    for (int c = nk - 1; c >= 0; --c) {
        double v = rhs[c];
        for (int j = c + 1; j < nk; ++j) v -= H[c][j] * x[j];
        double d = H[c][c]; if (fabs(d) < 1e-300) d = 1e-300;
        x[c] = v / d;
    }
    double sum = 0.0;
    for (int i = 0; i < nk; ++i) sum += x[i];
    if (sum == 0.0) sum = 1.0;
    for (int i = 0; i < 5; ++i) alphaOut[i] = (i < nk) ? (float)(x[i] / sum) : 0.f;
}

// ---------------- transpose + cast: W (f32 [k][n]) -> WT bf16 [n][k]
__global__ void k_transpose(const float* __restrict__ W, ushortT* __restrict__ WT) {
    __shared__ float tile[32][33];
    const int bx = blockIdx.x * 32, by = blockIdx.y * 32;
    const int tx = threadIdx.x, ty = threadIdx.y;  // (32,8)
#pragma unroll
    for (int r = 0; r < 32; r += 8)
        tile[ty + r][tx] = W[(size_t)(by + ty + r) * NDIM + bx + tx];
    __syncthreads();
#pragma unroll
    for (int r = 0; r < 32; r += 8)
        WT[(size_t)(bx + ty + r) * NDIM + by + tx] = f2bf(tile[tx][ty + r]);
}

// ---------------- init: F0 = tanh(u); G0 = F0 (X0=0); Xcur = F0; Abf = bf16(F0);
//                  dots[0] += <g0,g0>   (dots pre-zeroed by memset)
__global__ void k_init(const float* __restrict__ U, float* __restrict__ F0,
                       float* __restrict__ G0, float* __restrict__ Xcur,
                       ushortT* __restrict__ Abf, float* __restrict__ dots) {
    const int stride = gridDim.x * blockDim.x;
    float psum = 0.f;
    for (int i = blockIdx.x * blockDim.x + threadIdx.x; i < N4; i += stride) {
        float4 u = ((const float4*)U)[i];
        float4 t;
        t.x = tanh_fast(u.x); t.y = tanh_fast(u.y);
        t.z = tanh_fast(u.z); t.w = tanh_fast(u.w);
        ((float4*)F0)[i] = t;
        ((float4*)G0)[i] = t;
        ((float4*)Xcur)[i] = t;
        ushort4 p; p.x = f2bf(t.x); p.y = f2bf(t.y); p.z = f2bf(t.z); p.w = f2bf(t.w);
        ((ushort4*)Abf)[i] = p;
        psum += t.x * t.x + t.y * t.y + t.z * t.z + t.w * t.w;
    }
#pragma unroll
    for (int off = 32; off > 0; off >>= 1) psum += __shfl_down(psum, off);
    __shared__ float red[4];
    const int w = threadIdx.x >> 6, lane = threadIdx.x & 63;
    if (lane == 0) red[w] = psum;
    __syncthreads();
    if (threadIdx.x == 0)
        atomicAdd(dots, red[0] + red[1] + red[2] + red[3]);
}

// ---------------- GEMM: C = A(bf16)[128 rows] @ Bt(bf16)[64 rows]^T, BK=64, swizzled LDS
// MODE 0: out = tanh(C + U)
// MODE 1: jac += sum(((1-xstar^2)*C)^2)/NTOT          (A = eps)
// MODE 2: F = tanh(C+U); g = F - Xcur; G[s] = g; dots row/col s += <g, g_j> (j<cnt)
//
// LDS swizzle (m201 both-sides pattern): element A[R][c*8+e] (c=16B chunk idx in [0,8))
// is stored at lds[R*64 + (c^(R&7))*8 + e] (linear gload_lds dest; SOURCE address
// pre-swizzled: thread slot (R, cp) loads global chunk cp^(R&7)).  Reads XOR the same.
template <int MODE>
__global__ __launch_bounds__(256) void k_gemm(
    const ushortT* __restrict__ A, const ushortT* __restrict__ Bt,
    const float* __restrict__ U, float* __restrict__ Fout,
    const float* __restrict__ Xcur, float* __restrict__ G,
    float* __restrict__ dots, int s, int cnt,
    const float* __restrict__ xstar, float* __restrict__ jac) {
    __shared__ __align__(16) ushortT lA[2][128 * BK];
    __shared__ __align__(16) ushortT lB[2][64 * BK];
    const int tid = threadIdx.x;
    const int bm = blockIdx.y, bn = blockIdx.x;

    f32x4 acc[4][2] = {};

    const int w = tid >> 6, lane = tid & 63;
    const int wr = w >> 1, wc = w & 1;           // wave grid 2x2; wave tile 64x32
    const int lr = lane & 15, hi = lane >> 4;

#define STAGE(buf, kt) do {                                                               \
        _Pragma("unroll")                                                                 \
        for (int i = 0; i < 4; ++i) {                                                     \
            const int idx = i * 256 + tid;                                                \
            const int row = idx >> 3, c = (idx & 7) ^ (row & 7);                          \
            gload_lds16(A + (size_t)(bm * 128 + row) * NDIM + (kt) * BK + c * 8,          \
                        &lA[buf][idx * 8]);                                               \
        }                                                                                 \
        _Pragma("unroll")                                                                 \
        for (int i = 0; i < 2; ++i) {                                                     \
            const int idx = i * 256 + tid;                                                \
            const int row = idx >> 3, c = (idx & 7) ^ (row & 7);                          \
            gload_lds16(Bt + (size_t)(bn * 64 + row) * NDIM + (kt) * BK + c * 8,          \
                        &lB[buf][idx * 8]);                                               \
        }                                                                                 \
    } while (0)

    STAGE(0, 0);
    int cur = 0;
    for (int kt = 0; kt < NDIM / BK; ++kt) {
        __syncthreads();
        if (kt + 1 < NDIM / BK) STAGE(cur ^ 1, kt + 1);
#pragma unroll
        for (int h = 0; h < 2; ++h) {
            bf16x8 af[4], bfr[2];
#pragma unroll
            for (int m = 0; m < 4; ++m) {
                const int r = wr * 64 + m * 16 + lr;
                af[m] = *(const bf16x8*)&lA[cur][r * BK + (((h * 4 + hi) ^ (r & 7)) * 8)];
            }
#pragma unroll
            for (int n = 0; n < 2; ++n) {
                const int rb = wc * 32 + n * 16 + lr;
                bfr[n] = *(const bf16x8*)&lB[cur][rb * BK + (((h * 4 + hi) ^ (rb & 7)) * 8)];
            }
#pragma unroll
            for (int m = 0; m < 4; ++m)
#pragma unroll
                for (int n = 0; n < 2; ++n)
                    acc[m][n] = __builtin_amdgcn_mfma_f32_16x16x32_bf16(af[m], bfr[n], acc[m][n], 0, 0, 0);
        }
        cur ^= 1;
    }
#undef STAGE

    const int r0 = hi * 4;   // C/D: col = lane&15, row = hi*4 + reg
    if (MODE == 0) {
#pragma unroll
        for (int m = 0; m < 4; ++m) {
            const int row = bm * 128 + wr * 64 + m * 16 + r0;
#pragma unroll
            for (int n = 0; n < 2; ++n) {
                const int col = bn * 64 + wc * 32 + n * 16 + lr;
#pragma unroll
                for (int r = 0; r < 4; ++r) {
                    const size_t o = (size_t)(row + r) * NDIM + col;
                    Fout[o] = tanh_fast(acc[m][n][r] + U[o]);
                }
            }
        }
    } else if (MODE == 2) {
        float d[5] = {0.f, 0.f, 0.f, 0.f, 0.f};
#pragma unroll
        for (int m = 0; m < 4; ++m) {
            const int row = bm * 128 + wr * 64 + m * 16 + r0;
#pragma unroll
            for (int n = 0; n < 2; ++n) {
                const int col = bn * 64 + wc * 32 + n * 16 + lr;
#pragma unroll
                for (int r = 0; r < 4; ++r) {
                    const size_t o = (size_t)(row + r) * NDIM + col;
                    const float f = tanh_fast(acc[m][n][r] + U[o]);
                    Fout[o] = f;
                    const float g = f - Xcur[o];
                    G[(size_t)s * NTOT + o] = g;
#pragma unroll
                    for (int j = 0; j < 5; ++j)
                        if (j < cnt)
                            d[j] += g * ((j == s) ? g : G[(size_t)j * NTOT + o]);
                }
            }
        }
        __syncthreads();                       // LDS reuse for reduction
        float* red = (float*)lA;               // [4 waves][5]
#pragma unroll
        for (int j = 0; j < 5; ++j) {
            float v = d[j];
#pragma unroll
            for (int off = 32; off > 0; off >>= 1) v += __shfl_down(v, off);
            if (lane == 0) red[w * 5 + j] = v;
        }
        __syncthreads();
        if (tid < 5 && tid < cnt) {
            const float v = red[tid] + red[5 + tid] + red[10 + tid] + red[15 + tid];
            atomicAdd(&dots[s * 5 + tid], v);
            if (tid != s) atomicAdd(&dots[tid * 5 + s], v);
        }
    } else {  // MODE 1: Hutchinson accumulate
        float psum = 0.f;
#pragma unroll
        for (int m = 0; m < 4; ++m) {
            const int row = bm * 128 + wr * 64 + m * 16 + r0;
#pragma unroll
            for (int n = 0; n < 2; ++n) {
                const int col = bn * 64 + wc * 32 + n * 16 + lr;
#pragma unroll
                for (int r = 0; r < 4; ++r) {
                    const size_t o = (size_t)(row + r) * NDIM + col;
                    const float t = xstar[o];
                    const float tang = (1.f - t * t) * acc[m][n][r];
                    psum += tang * tang;
                }
            }
        }
#pragma unroll
        for (int off = 32; off > 0; off >>= 1) psum += __shfl_down(psum, off);
        __syncthreads();
        float* red = (float*)lA;
        if (lane == 0) red[w] = psum;
        __syncthreads();
        if (tid == 0)
            atomicAdd(jac, (red[0] + red[1] + red[2] + red[3]) * (1.0f / (float)NTOT));
    }
}

// ---------------- mix: per-block redundant alpha solve; Xcur = sum a_j F_j; Abf = bf16(Xcur)
//                  finisher-block zeroes dots row/col s (+counter) for next GEMM's accumulation
__global__ void k_mix(const float* __restrict__ F, float* __restrict__ dots,
                      float* __restrict__ Xcur, ushortT* __restrict__ Abf,
                      int nk, int s) {
    __shared__ float sa[5];
    if (threadIdx.x == 0) solve5(dots, sa, nk);
    __syncthreads();
    float a[5];
#pragma unroll
    for (int i = 0; i < 5; ++i) a[i] = sa[i];

    const int stride = gridDim.x * blockDim.x;
    for (int i = blockIdx.x * blockDim.x + threadIdx.x; i < N4; i += stride) {
        float4 sv = make_float4(0.f, 0.f, 0.f, 0.f);
#pragma unroll
        for (int j = 0; j < 5; ++j)
            if (j < nk) {
                float4 f = ((const float4*)(F + (size_t)j * NTOT))[i];
                sv.x += a[j] * f.x; sv.y += a[j] * f.y;
                sv.z += a[j] * f.z; sv.w += a[j] * f.w;
            }
        ((float4*)Xcur)[i] = sv;
        ushort4 p; p.x = f2bf(sv.x); p.y = f2bf(sv.y); p.z = f2bf(sv.z); p.w = f2bf(sv.w);
        ((ushort4*)Abf)[i] = p;
    }
    // finisher: all blocks have read dots (prologue) once counter hits gridDim-1
    if (threadIdx.x == 0) {
        int* counter = (int*)(dots + 31);
        const int old = atomicAdd(counter, 1);
        if (old == (int)gridDim.x - 1) {
#pragma unroll
            for (int j = 0; j < 5; ++j) { dots[s * 5 + j] = 0.f; dots[j * 5 + s] = 0.f; }
            atomicExch(counter, 0);
        }
    }
}

// ---------------- eps: Rademacher +/-1 in bf16
__global__ void k_eps(ushortT* __restrict__ E) {
    const int stride = gridDim.x * blockDim.x;
    for (int i = blockIdx.x * blockDim.x + threadIdx.x; i < N4; i += stride) {
        ushort4 p;
        p.x = (hash_u32(4u * i + 0u) & 1u) ? 0xBF80u : 0x3F80u;
        p.y = (hash_u32(4u * i + 1u) & 1u) ? 0xBF80u : 0x3F80u;
        p.z = (hash_u32(4u * i + 2u) & 1u) ? 0xBF80u : 0x3F80u;
        p.w = (hash_u32(4u * i + 3u) & 1u) ? 0xBF80u : 0x3F80u;
        ((ushort4*)E)[i] = p;
    }
}

extern "C" void kernel_launch(void* const* d_in, const int* in_sizes, int n_in,
                              void* d_out, int out_size, void* d_ws, size_t ws_size,
                              hipStream_t stream) {
    const float* W = (const float*)d_in[1];   // d_in[0] = x unused (x0 = zeros)
    const float* U = (const float*)d_in[2];
    float* out = (float*)d_out;

    // ws: WT bf16 8MB | Abf bf16 8MB (reused as eps) | F[5] f32 80MB | G[5] f32 80MB | Xcur 16MB | dots 32f
    ushortT* WT  = (ushortT*)d_ws;
    ushortT* Abf = WT + (size_t)NTOT;
    float* Fs    = (float*)(Abf + (size_t)NTOT);
    float* Gs    = Fs + (size_t)5 * NTOT;
    float* Xcur  = Gs + (size_t)5 * NTOT;
    float* dots  = Xcur + (size_t)NTOT;

    hipMemsetAsync(dots, 0, 32 * sizeof(float), stream);    // dots + finisher counter
    hipMemsetAsync(out + NTOT, 0, sizeof(float), stream);   // jac accumulator

    k_transpose<<<dim3(64, 64), dim3(32, 8), 0, stream>>>(W, WT);
    k_init<<<1024, 256, 0, stream>>>(U, Fs, Gs, Xcur, Abf, dots);
    // F1 = tanh(F0 @ W + u); G1 = F1 - F0; dots row/col 1 (cnt=2)
    k_gemm<2><<<GEMM_GRID, 256, 0, stream>>>(Abf, WT, U, Fs + NTOT, Xcur, Gs, dots,
                                             1, 2, nullptr, nullptr);
    for (int k = 2; k < 19; ++k) {
        const int s = k % 5;
        const int nk = k < 5 ? k : 5;
        const int cnt = (k + 1 < 5) ? (k + 1) : 5;
        k_mix<<<1024, 256, 0, stream>>>(Fs, dots, Xcur, Abf, nk, s);
        k_gemm<2><<<GEMM_GRID, 256, 0, stream>>>(Abf, WT, U, Fs + (size_t)s * NTOT,
                                                 Xcur, Gs, dots, s, cnt, nullptr, nullptr);
    }
    // k = 19: final iterate straight to d_out (no dots needed)
    k_mix<<<1024, 256, 0, stream>>>(Fs, dots, Xcur, Abf, 5, 4);
    k_gemm<0><<<GEMM_GRID, 256, 0, stream>>>(Abf, WT, U, out, nullptr, nullptr, nullptr,
                                             0, 0, nullptr, nullptr);
    // jac_reg: independent Rademacher Hutchinson probe
    k_eps<<<1024, 256, 0, stream>>>(Abf);
    k_gemm<1><<<GEMM_GRID, 256, 0, stream>>>(Abf, WT, nullptr, nullptr, nullptr, nullptr,
                                             nullptr, 0, 0, out, out + NTOT);
}

// Round 5
// 2133.613 us; speedup vs baseline: 1.1840x; 1.1352x over previous
//
#include <hip/hip_runtime.h>

typedef unsigned short ushortT;
typedef short bf16x8 __attribute__((ext_vector_type(8)));   // 8 bf16 in 4 VGPRs
typedef float f32x4 __attribute__((ext_vector_type(4)));

#define NDIM 2048
#define NTOT (2048 * 2048)
#define N4 (NTOT / 4)
#define N8 (NTOT / 8)
#define BK 64
#define GEMM_GRID dim3(32, 32)   // bn x bm : 64x64 tiles -> 1024 blocks (4/CU)

__device__ __forceinline__ ushortT f2bf(float f) {
    unsigned u = __float_as_uint(f);
    u += 0x7fffu + ((u >> 16) & 1u);   // RNE; inputs finite
    return (ushortT)(u >> 16);
}
__device__ __forceinline__ float bf2f(ushortT u) {
    return __uint_as_float((unsigned)u << 16);
}
__device__ __forceinline__ float tanh_fast(float x) {
    float e = __expf(2.0f * x);
    return 1.0f - 2.0f / (e + 1.0f);
}
__device__ __forceinline__ void gload_lds16(const void* g, void* l) {
    __builtin_amdgcn_global_load_lds(
        (const __attribute__((address_space(1))) void*)g,
        (__attribute__((address_space(3))) void*)l, 16, 0, 0);
}
__device__ __forceinline__ unsigned hash_u32(unsigned x) {
    x ^= x >> 16; x *= 0x7feb352du; x ^= x >> 15; x *= 0x846ca68bu; x ^= x >> 16;
    return x;
}

// 5x5 ridge-normal-equation solve (LU w/ pivoting, fp64), alpha normalized.
__device__ void solve5(const float* dots, float* alphaOut, int nk) {
    double H[5][5], rhs[5], x[5];
    for (int i = 0; i < nk; ++i) {
        for (int j = 0; j < nk; ++j)
            H[i][j] = (double)dots[i * 5 + j] + (i == j ? 1e-4 : 0.0);
        rhs[i] = 1.0;
    }
    for (int c = 0; c < nk; ++c) {
        int p = c; double mx = fabs(H[c][c]);
        for (int r = c + 1; r < nk; ++r) { double a = fabs(H[r][c]); if (a > mx) { mx = a; p = r; } }
        if (p != c) {
            for (int j = 0; j < nk; ++j) { double tv = H[c][j]; H[c][j] = H[p][j]; H[p][j] = tv; }
            double tr = rhs[c]; rhs[c] = rhs[p]; rhs[p] = tr;
        }
        double d = H[c][c]; if (fabs(d) < 1e-300) d = 1e-300;
        for (int r = c + 1; r < nk; ++r) {
            double f = H[r][c] / d;
            for (int j = c; j < nk; ++j) H[r][j] -= f * H[c][j];
            rhs[r] -= f * rhs[c];
        }
    }
    for (int c = nk - 1; c >= 0; --c) {
        double v = rhs[c];
        for (int j = c + 1; j < nk; ++j) v -= H[c][j] * x[j];
        double d = H[c][c]; if (fabs(d) < 1e-300) d = 1e-300;
        x[c] = v / d;
    }
    double sum = 0.0;
    for (int i = 0; i < nk; ++i) sum += x[i];
    if (sum == 0.0) sum = 1.0;
    for (int i = 0; i < 5; ++i) alphaOut[i] = (i < nk) ? (float)(x[i] / sum) : 0.f;
}

// ---------------- transpose + cast: W (f32 [k][n]) -> WT bf16 [n][k]
__global__ void k_transpose(const float* __restrict__ W, ushortT* __restrict__ WT) {
    __shared__ float tile[32][33];
    const int bx = blockIdx.x * 32, by = blockIdx.y * 32;
    const int tx = threadIdx.x, ty = threadIdx.y;  // (32,8)
#pragma unroll
    for (int r = 0; r < 32; r += 8)
        tile[ty + r][tx] = W[(size_t)(by + ty + r) * NDIM + bx + tx];
    __syncthreads();
#pragma unroll
    for (int r = 0; r < 32; r += 8)
        WT[(size_t)(bx + ty + r) * NDIM + by + tx] = f2bf(tile[tx][ty + r]);
}

// ---------------- init: F0 = tanh(u); G0(bf16) = F0 (X0=0); Xcur = F0; Abf = bf16(F0);
//                  dots[0][0] += <g0,g0>  (dots pre-zeroed by memset)
__global__ void k_init(const float* __restrict__ U, float* __restrict__ F0,
                       ushortT* __restrict__ G0, float* __restrict__ Xcur,
                       ushortT* __restrict__ Abf, float* __restrict__ dots) {
    const int stride = gridDim.x * blockDim.x;
    float psum = 0.f;
    for (int i = blockIdx.x * blockDim.x + threadIdx.x; i < N4; i += stride) {
        float4 u = ((const float4*)U)[i];
        float4 t;
        t.x = tanh_fast(u.x); t.y = tanh_fast(u.y);
        t.z = tanh_fast(u.z); t.w = tanh_fast(u.w);
        ((float4*)F0)[i] = t;
        ((float4*)Xcur)[i] = t;
        ushort4 p; p.x = f2bf(t.x); p.y = f2bf(t.y); p.z = f2bf(t.z); p.w = f2bf(t.w);
        ((ushort4*)G0)[i] = p;
        ((ushort4*)Abf)[i] = p;
        // dot of the STORED (bf16-rounded) residual, consistent with k_dotsG
        float a = bf2f(p.x), b = bf2f(p.y), c = bf2f(p.z), d = bf2f(p.w);
        psum += a * a + b * b + c * c + d * d;
    }
#pragma unroll
    for (int off = 32; off > 0; off >>= 1) psum += __shfl_down(psum, off);
    __shared__ float red[4];
    const int w = threadIdx.x >> 6, lane = threadIdx.x & 63;
    if (lane == 0) red[w] = psum;
    __syncthreads();
    if (threadIdx.x == 0)
        atomicAdd(dots, red[0] + red[1] + red[2] + red[3]);
}

// ---------------- GEMM: C = A(bf16)[64 rows] @ Bt(bf16)[64 rows]^T, BK=64, swizzled LDS
// MODE 0: Fout = tanh(C + U)
// MODE 1: jac += sum(((1-xstar^2)*C)^2)/NTOT            (A = eps)
// MODE 2: F = tanh(C+U); G[s] = bf16(F - Xcur)          (dots done by k_dotsG)
//
// LDS swizzle (both-sides, rule #21): slot (row, cp) receives global chunk cp^(row&7)
// (linear gload_lds dest, pre-swizzled source); reads XOR the same involution.
template <int MODE>
__global__ __launch_bounds__(256) void k_gemm(
    const ushortT* __restrict__ A, const ushortT* __restrict__ Bt,
    const float* __restrict__ U, float* __restrict__ Fout,
    const float* __restrict__ Xcur, ushortT* __restrict__ G, int s,
    const float* __restrict__ xstar, float* __restrict__ jac) {
    __shared__ __align__(16) ushortT lA[2][64 * BK];
    __shared__ __align__(16) ushortT lB[2][64 * BK];
    const int tid = threadIdx.x;
    const int bm = blockIdx.y, bn = blockIdx.x;

    f32x4 acc[2][2] = {};

    const int w = tid >> 6, lane = tid & 63;
    const int wr = w >> 1, wc = w & 1;           // wave grid 2x2; wave tile 32x32
    const int lr = lane & 15, hi = lane >> 4;

#define STAGE(buf, kt) do {                                                               \
        _Pragma("unroll")                                                                 \
        for (int i = 0; i < 2; ++i) {                                                     \
            const int idx = i * 256 + tid;                                                \
            const int row = idx >> 3, c = (idx & 7) ^ (row & 7);                          \
            gload_lds16(A + (size_t)(bm * 64 + row) * NDIM + (kt) * BK + c * 8,           \
                        &lA[buf][idx * 8]);                                               \
        }                                                                                 \
        _Pragma("unroll")                                                                 \
        for (int i = 0; i < 2; ++i) {                                                     \
            const int idx = i * 256 + tid;                                                \
            const int row = idx >> 3, c = (idx & 7) ^ (row & 7);                          \
            gload_lds16(Bt + (size_t)(bn * 64 + row) * NDIM + (kt) * BK + c * 8,          \
                        &lB[buf][idx * 8]);                                               \
        }                                                                                 \
    } while (0)

    STAGE(0, 0);
    int cur = 0;
    for (int kt = 0; kt < NDIM / BK; ++kt) {
        __syncthreads();
        if (kt + 1 < NDIM / BK) STAGE(cur ^ 1, kt + 1);
#pragma unroll
        for (int h = 0; h < 2; ++h) {
            bf16x8 af[2], bfr[2];
#pragma unroll
            for (int m = 0; m < 2; ++m) {
                const int r = wr * 32 + m * 16 + lr;
                af[m] = *(const bf16x8*)&lA[cur][r * BK + (((h * 4 + hi) ^ (r & 7)) * 8)];
            }
#pragma unroll
            for (int n = 0; n < 2; ++n) {
                const int rb = wc * 32 + n * 16 + lr;
                bfr[n] = *(const bf16x8*)&lB[cur][rb * BK + (((h * 4 + hi) ^ (rb & 7)) * 8)];
            }
#pragma unroll
            for (int m = 0; m < 2; ++m)
#pragma unroll
                for (int n = 0; n < 2; ++n)
                    acc[m][n] = __builtin_amdgcn_mfma_f32_16x16x32_bf16(af[m], bfr[n], acc[m][n], 0, 0, 0);
        }
        cur ^= 1;
    }
#undef STAGE

    const int r0 = hi * 4;   // C/D: col = lane&15, row = hi*4 + reg
    if (MODE == 0) {
#pragma unroll
        for (int m = 0; m < 2; ++m) {
            const int row = bm * 64 + wr * 32 + m * 16 + r0;
#pragma unroll
            for (int n = 0; n < 2; ++n) {
                const int col = bn * 64 + wc * 32 + n * 16 + lr;
#pragma unroll
                for (int r = 0; r < 4; ++r) {
                    const size_t o = (size_t)(row + r) * NDIM + col;
                    Fout[o] = tanh_fast(acc[m][n][r] + U[o]);
                }
            }
        }
    } else if (MODE == 2) {
#pragma unroll
        for (int m = 0; m < 2; ++m) {
            const int row = bm * 64 + wr * 32 + m * 16 + r0;
#pragma unroll
            for (int n = 0; n < 2; ++n) {
                const int col = bn * 64 + wc * 32 + n * 16 + lr;
#pragma unroll
                for (int r = 0; r < 4; ++r) {
                    const size_t o = (size_t)(row + r) * NDIM + col;
                    const float f = tanh_fast(acc[m][n][r] + U[o]);
                    Fout[o] = f;
                    G[(size_t)s * NTOT + o] = f2bf(f - Xcur[o]);
                }
            }
        }
    } else {  // MODE 1: Hutchinson accumulate
        float psum = 0.f;
#pragma unroll
        for (int m = 0; m < 2; ++m) {
            const int row = bm * 64 + wr * 32 + m * 16 + r0;
#pragma unroll
            for (int n = 0; n < 2; ++n) {
                const int col = bn * 64 + wc * 32 + n * 16 + lr;
#pragma unroll
                for (int r = 0; r < 4; ++r) {
                    const size_t o = (size_t)(row + r) * NDIM + col;
                    const float t = xstar[o];
                    const float tang = (1.f - t * t) * acc[m][n][r];
                    psum += tang * tang;
                }
            }
        }
#pragma unroll
        for (int off = 32; off > 0; off >>= 1) psum += __shfl_down(psum, off);
        __syncthreads();
        float* red = (float*)lA;
        if (lane == 0) red[w] = psum;
        __syncthreads();
        if (tid == 0)
            atomicAdd(jac, (red[0] + red[1] + red[2] + red[3]) * (1.0f / (float)NTOT));
    }
}

// ---------------- dots on bf16 residuals: row/col s of gram: <g_s, g_j> for j < cnt
__global__ void k_dotsG(const ushortT* __restrict__ G, float* dots, int s, int cnt) {
    float d[5] = {0.f, 0.f, 0.f, 0.f, 0.f};
    const int stride = gridDim.x * blockDim.x;
    const ushort4* G4 = (const ushort4*)G;   // stride-2 indexing gives 8 bf16 per iter
    for (int i = blockIdx.x * blockDim.x + threadIdx.x; i < N8; i += stride) {
        ushort4 s0 = G4[(size_t)s * (NTOT / 4) + 2 * i];
        ushort4 s1 = G4[(size_t)s * (NTOT / 4) + 2 * i + 1];
        float gs[8] = {bf2f(s0.x), bf2f(s0.y), bf2f(s0.z), bf2f(s0.w),
                       bf2f(s1.x), bf2f(s1.y), bf2f(s1.z), bf2f(s1.w)};
#pragma unroll
        for (int j = 0; j < 5; ++j)
            if (j < cnt) {
                if (j == s) {
#pragma unroll
                    for (int e = 0; e < 8; ++e) d[j] += gs[e] * gs[e];
                } else {
                    ushort4 a0 = G4[(size_t)j * (NTOT / 4) + 2 * i];
                    ushort4 a1 = G4[(size_t)j * (NTOT / 4) + 2 * i + 1];
                    d[j] += gs[0] * bf2f(a0.x) + gs[1] * bf2f(a0.y) +
                            gs[2] * bf2f(a0.z) + gs[3] * bf2f(a0.w) +
                            gs[4] * bf2f(a1.x) + gs[5] * bf2f(a1.y) +
                            gs[6] * bf2f(a1.z) + gs[7] * bf2f(a1.w);
                }
            }
    }
    const int w = threadIdx.x >> 6, lane = threadIdx.x & 63;
    __shared__ float red[4][5];
#pragma unroll
    for (int j = 0; j < 5; ++j) {
        float v = d[j];
#pragma unroll
        for (int off = 32; off > 0; off >>= 1) v += __shfl_down(v, off);
        if (lane == 0) red[w][j] = v;
    }
    __syncthreads();
    if (threadIdx.x < 5 && (int)threadIdx.x < cnt) {
        const int j = threadIdx.x;
        const float v = red[0][j] + red[1][j] + red[2][j] + red[3][j];
        atomicAdd(&dots[s * 5 + j], v);
        if (j != s) atomicAdd(&dots[j * 5 + s], v);
    }
}

// ---------------- mix: per-block redundant alpha solve; Xcur = sum a_j F_j; Abf = bf16(Xcur)
//                  finisher-block zeroes dots row/col s for the next GEMM's accumulation
__global__ void k_mix(const float* __restrict__ F, float* __restrict__ dots,
                      float* __restrict__ Xcur, ushortT* __restrict__ Abf,
                      int nk, int s) {
    __shared__ float sa[5];
    if (threadIdx.x == 0) solve5(dots, sa, nk);
    __syncthreads();
    float a[5];
#pragma unroll
    for (int i = 0; i < 5; ++i) a[i] = sa[i];

    const int stride = gridDim.x * blockDim.x;
    for (int i = blockIdx.x * blockDim.x + threadIdx.x; i < N4; i += stride) {
        float4 sv = make_float4(0.f, 0.f, 0.f, 0.f);
#pragma unroll
        for (int j = 0; j < 5; ++j)
            if (j < nk) {
                float4 f = ((const float4*)(F + (size_t)j * NTOT))[i];
                sv.x += a[j] * f.x; sv.y += a[j] * f.y;
                sv.z += a[j] * f.z; sv.w += a[j] * f.w;
            }
        ((float4*)Xcur)[i] = sv;
        ushort4 p; p.x = f2bf(sv.x); p.y = f2bf(sv.y); p.z = f2bf(sv.z); p.w = f2bf(sv.w);
        ((ushort4*)Abf)[i] = p;
    }
    // finisher: all blocks have read dots (solve5 prologue) before the counter saturates
    if (threadIdx.x == 0) {
        int* counter = (int*)(dots + 31);
        const int old = atomicAdd(counter, 1);
        if (old == (int)gridDim.x - 1) {
#pragma unroll
            for (int j = 0; j < 5; ++j) { dots[s * 5 + j] = 0.f; dots[j * 5 + s] = 0.f; }
            atomicExch(counter, 0);
        }
    }
}

// ---------------- eps: Rademacher +/-1 in bf16
__global__ void k_eps(ushortT* __restrict__ E) {
    const int stride = gridDim.x * blockDim.x;
    for (int i = blockIdx.x * blockDim.x + threadIdx.x; i < N4; i += stride) {
        ushort4 p;
        p.x = (hash_u32(4u * i + 0u) & 1u) ? 0xBF80u : 0x3F80u;
        p.y = (hash_u32(4u * i + 1u) & 1u) ? 0xBF80u : 0x3F80u;
        p.z = (hash_u32(4u * i + 2u) & 1u) ? 0xBF80u : 0x3F80u;
        p.w = (hash_u32(4u * i + 3u) & 1u) ? 0xBF80u : 0x3F80u;
        ((ushort4*)E)[i] = p;
    }
}

extern "C" void kernel_launch(void* const* d_in, const int* in_sizes, int n_in,
                              void* d_out, int out_size, void* d_ws, size_t ws_size,
                              hipStream_t stream) {
    const float* W = (const float*)d_in[1];   // d_in[0] = x unused (x0 = zeros)
    const float* U = (const float*)d_in[2];
    float* out = (float*)d_out;

    // ws: WT bf16 8MB | Abf bf16 8MB (reused as eps) | F[5] f32 80MB | G[5] bf16 40MB | Xcur 16MB | dots 32f
    ushortT* WT  = (ushortT*)d_ws;
    ushortT* Abf = WT + (size_t)NTOT;
    float* Fs    = (float*)(Abf + (size_t)NTOT);
    ushortT* Gs  = (ushortT*)(Fs + (size_t)5 * NTOT);
    float* Xcur  = (float*)(Gs + (size_t)5 * NTOT);
    float* dots  = Xcur + (size_t)NTOT;

    hipMemsetAsync(dots, 0, 32 * sizeof(float), stream);    // dots + finisher counter
    hipMemsetAsync(out + NTOT, 0, sizeof(float), stream);   // jac accumulator

    k_transpose<<<dim3(64, 64), dim3(32, 8), 0, stream>>>(W, WT);
    k_init<<<1024, 256, 0, stream>>>(U, Fs, Gs, Xcur, Abf, dots);
    // k=1: F1 = tanh(F0 @ W + u); G1 = bf16(F1 - F0); dots row/col 1 (cnt=2)
    k_gemm<2><<<GEMM_GRID, 256, 0, stream>>>(Abf, WT, U, Fs + NTOT, Xcur, Gs, 1,
                                             nullptr, nullptr);
    k_dotsG<<<1024, 256, 0, stream>>>(Gs, dots, 1, 2);
    for (int k = 2; k < 19; ++k) {
        const int s = k % 5;
        const int nk = k < 5 ? k : 5;
        const int cnt = (k + 1 < 5) ? (k + 1) : 5;
        k_mix<<<1024, 256, 0, stream>>>(Fs, dots, Xcur, Abf, nk, s);
        k_gemm<2><<<GEMM_GRID, 256, 0, stream>>>(Abf, WT, U, Fs + (size_t)s * NTOT,
                                                 Xcur, Gs, s, nullptr, nullptr);
        k_dotsG<<<1024, 256, 0, stream>>>(Gs, dots, s, cnt);
    }
    // k = 19: final iterate straight to d_out (no dots needed)
    k_mix<<<1024, 256, 0, stream>>>(Fs, dots, Xcur, Abf, 5, 4);
    k_gemm<0><<<GEMM_GRID, 256, 0, stream>>>(Abf, WT, U, out, nullptr, nullptr, 0,
                                             nullptr, nullptr);
    // jac_reg: independent Rademacher Hutchinson probe
    k_eps<<<1024, 256, 0, stream>>>(Abf);
    k_gemm<1><<<GEMM_GRID, 256, 0, stream>>>(Abf, WT, nullptr, nullptr, nullptr, nullptr, 0,
                                             out, out + NTOT);
}

// Round 7
// 2002.019 us; speedup vs baseline: 1.2619x; 1.0657x over previous
//
#include <hip/hip_runtime.h>

typedef unsigned short ushortT;
typedef short bf16x8 __attribute__((ext_vector_type(8)));   // 8 bf16 in 4 VGPRs
typedef float f32x4 __attribute__((ext_vector_type(4)));

#define NDIM 2048
#define NTOT (2048 * 2048)
#define N4 (NTOT / 4)
#define N8 (NTOT / 8)
#define BK 64
#define GEMM_BLOCKS 1024   // 64x64 tiles on 32x32 grid, XCD-supertiled

__device__ __forceinline__ ushortT f2bf(float f) {
    unsigned u = __float_as_uint(f);
    u += 0x7fffu + ((u >> 16) & 1u);   // RNE; inputs finite
    return (ushortT)(u >> 16);
}
__device__ __forceinline__ float bf2f(ushortT u) {
    return __uint_as_float((unsigned)u << 16);
}
__device__ __forceinline__ float tanh_fast(float x) {
    float e = __expf(2.0f * x);
    return 1.0f - 2.0f / (e + 1.0f);
}
__device__ __forceinline__ void gload_lds16(const void* g, void* l) {
    __builtin_amdgcn_global_load_lds(
        (const __attribute__((address_space(1))) void*)g,
        (__attribute__((address_space(3))) void*)l, 16, 0, 0);
}
__device__ __forceinline__ unsigned hash_u32(unsigned x) {
    x ^= x >> 16; x *= 0x7feb352du; x ^= x >> 15; x *= 0x846ca68bu; x ^= x >> 16;
    return x;
}

// 5x5 ridge-normal-equation solve (LU w/ pivoting, fp64), alpha normalized.
__device__ void solve5(const float* dots, float* alphaOut, int nk) {
    double H[5][5], rhs[5], x[5];
    for (int i = 0; i < nk; ++i) {
        for (int j = 0; j < nk; ++j)
            H[i][j] = (double)dots[i * 5 + j] + (i == j ? 1e-4 : 0.0);
        rhs[i] = 1.0;
    }
    for (int c = 0; c < nk; ++c) {
        int p = c; double mx = fabs(H[c][c]);
        for (int r = c + 1; r < nk; ++r) { double a = fabs(H[r][c]); if (a > mx) { mx = a; p = r; } }
        if (p != c) {
            for (int j = 0; j < nk; ++j) { double tv = H[c][j]; H[c][j] = H[p][j]; H[p][j] = tv; }
            double tr = rhs[c]; rhs[c] = rhs[p]; rhs[p] = tr;
        }
        double d = H[c][c]; if (fabs(d) < 1e-300) d = 1e-300;
        for (int r = c + 1; r < nk; ++r) {
            double f = H[r][c] / d;
            for (int j = c; j < nk; ++j) H[r][j] -= f * H[c][j];
            rhs[r] -= f * rhs[c];
        }
    }
    for (int c = nk - 1; c >= 0; --c) {
        double v = rhs[c];
        for (int j = c + 1; j < nk; ++j) v -= H[c][j] * x[j];
        double d = H[c][c]; if (fabs(d) < 1e-300) d = 1e-300;
        x[c] = v / d;
    }
    double sum = 0.0;
    for (int i = 0; i < nk; ++i) sum += x[i];
    if (sum == 0.0) sum = 1.0;
    for (int i = 0; i < 5; ++i) alphaOut[i] = (i < nk) ? (float)(x[i] / sum) : 0.f;
}

// ---------------- transpose + cast: W (f32 [k][n]) -> WT bf16 [n][k]
__global__ void k_transpose(const float* __restrict__ W, ushortT* __restrict__ WT) {
    __shared__ float tile[32][33];
    const int bx = blockIdx.x * 32, by = blockIdx.y * 32;
    const int tx = threadIdx.x, ty = threadIdx.y;  // (32,8)
#pragma unroll
    for (int r = 0; r < 32; r += 8)
        tile[ty + r][tx] = W[(size_t)(by + ty + r) * NDIM + bx + tx];
    __syncthreads();
#pragma unroll
    for (int r = 0; r < 32; r += 8)
        WT[(size_t)(bx + ty + r) * NDIM + by + tx] = f2bf(tile[tx][ty + r]);
}

// ---------------- init: F0(bf16) = G0(bf16) = Abf = bf16(tanh(u)); Xcur(f32) = tanh(u);
//                  dots[0][0] += <g0,g0>  (dots pre-zeroed by memset)
__global__ void k_init(const float* __restrict__ U, ushortT* __restrict__ F0,
                       ushortT* __restrict__ G0, float* __restrict__ Xcur,
                       ushortT* __restrict__ Abf, float* __restrict__ dots) {
    const int stride = gridDim.x * blockDim.x;
    float psum = 0.f;
    for (int i = blockIdx.x * blockDim.x + threadIdx.x; i < N4; i += stride) {
        float4 u = ((const float4*)U)[i];
        float4 t;
        t.x = tanh_fast(u.x); t.y = tanh_fast(u.y);
        t.z = tanh_fast(u.z); t.w = tanh_fast(u.w);
        ((float4*)Xcur)[i] = t;
        ushort4 p; p.x = f2bf(t.x); p.y = f2bf(t.y); p.z = f2bf(t.z); p.w = f2bf(t.w);
        ((ushort4*)F0)[i] = p;
        ((ushort4*)G0)[i] = p;
        ((ushort4*)Abf)[i] = p;
        // dot of the STORED (bf16-rounded) residual, consistent with k_dotsG
        float a = bf2f(p.x), b = bf2f(p.y), c = bf2f(p.z), d = bf2f(p.w);
        psum += a * a + b * b + c * c + d * d;
    }
#pragma unroll
    for (int off = 32; off > 0; off >>= 1) psum += __shfl_down(psum, off);
    __shared__ float red[4];
    const int w = threadIdx.x >> 6, lane = threadIdx.x & 63;
    if (lane == 0) red[w] = psum;
    __syncthreads();
    if (threadIdx.x == 0)
        atomicAdd(dots, red[0] + red[1] + red[2] + red[3]);
}

// ---------------- GEMM: C = A(bf16)[64 rows] @ Bt(bf16)[64 rows]^T, BK=64, swizzled LDS
// MODE 0: (float*)FoutV = tanh(C + U)                      [f32 final output]
// MODE 1: jac += sum(((1-xstar^2)*C)^2)/NTOT               (A = eps)
// MODE 2: f = tanh(C+U); (ushort*)FoutV = bf16(f); G[s] = bf16(f - Xcur)
//
// Grid: 1D, XCD-supertiled. blockIdx round-robins XCDs (xcd = id&7, m09); chunk=id&7
// owns a contiguous 8(bm)x16(bn) supertile -> per-XCD panel footprint 6 MB.
// LDS swizzle (both-sides, rule #21): slot (row, cp) receives global chunk cp^(row&7).
template <int MODE>
__global__ __launch_bounds__(256) void k_gemm(
    const ushortT* __restrict__ A, const ushortT* __restrict__ Bt,
    const float* __restrict__ U, void* __restrict__ FoutV,
    const float* __restrict__ Xcur, ushortT* __restrict__ G, int s,
    const float* __restrict__ xstar, float* __restrict__ jac) {
    __shared__ __align__(16) ushortT lA[2][64 * BK];
    __shared__ __align__(16) ushortT lB[2][64 * BK];
    const int tid = threadIdx.x;
    // XCD supertile remap: chunk-grid 4x2 of 8x16 supertiles
    const int wg = blockIdx.x;
    const int chunk = wg & 7, pos = wg >> 3;
    const int bm = (chunk >> 1) * 8 + (pos >> 4);
    const int bn = (chunk & 1) * 16 + (pos & 15);

    f32x4 acc[2][2] = {};

    const int w = tid >> 6, lane = tid & 63;
    const int wr = w >> 1, wc = w & 1;           // wave grid 2x2; wave tile 32x32
    const int lr = lane & 15, hi = lane >> 4;

#define STAGE(buf, kt) do {                                                               \
        _Pragma("unroll")                                                                 \
        for (int i = 0; i < 2; ++i) {                                                     \
            const int idx = i * 256 + tid;                                                \
            const int row = idx >> 3, c = (idx & 7) ^ (row & 7);                          \
            gload_lds16(A + (size_t)(bm * 64 + row) * NDIM + (kt) * BK + c * 8,           \
                        &lA[buf][idx * 8]);                                               \
        }                                                                                 \
        _Pragma("unroll")                                                                 \
        for (int i = 0; i < 2; ++i) {                                                     \
            const int idx = i * 256 + tid;                                                \
            const int row = idx >> 3, c = (idx & 7) ^ (row & 7);                          \
            gload_lds16(Bt + (size_t)(bn * 64 + row) * NDIM + (kt) * BK + c * 8,          \
                        &lB[buf][idx * 8]);                                               \
        }                                                                                 \
    } while (0)

    STAGE(0, 0);
    int cur = 0;
    for (int kt = 0; kt < NDIM / BK; ++kt) {
        __syncthreads();
        if (kt + 1 < NDIM / BK) STAGE(cur ^ 1, kt + 1);
#pragma unroll
        for (int h = 0; h < 2; ++h) {
            bf16x8 af[2], bfr[2];
#pragma unroll
            for (int m = 0; m < 2; ++m) {
                const int r = wr * 32 + m * 16 + lr;
                af[m] = *(const bf16x8*)&lA[cur][r * BK + (((h * 4 + hi) ^ (r & 7)) * 8)];
            }
#pragma unroll
            for (int n = 0; n < 2; ++n) {
                const int rb = wc * 32 + n * 16 + lr;
                bfr[n] = *(const bf16x8*)&lB[cur][rb * BK + (((h * 4 + hi) ^ (rb & 7)) * 8)];
            }
#pragma unroll
            for (int m = 0; m < 2; ++m)
#pragma unroll
                for (int n = 0; n < 2; ++n)
                    acc[m][n] = __builtin_amdgcn_mfma_f32_16x16x32_bf16(af[m], bfr[n], acc[m][n], 0, 0, 0);
        }
        cur ^= 1;
    }
#undef STAGE

    const int r0 = hi * 4;   // C/D: col = lane&15, row = hi*4 + reg
    if (MODE == 0) {
        float* Fout = (float*)FoutV;
#pragma unroll
        for (int m = 0; m < 2; ++m) {
            const int row = bm * 64 + wr * 32 + m * 16 + r0;
#pragma unroll
            for (int n = 0; n < 2; ++n) {
                const int col = bn * 64 + wc * 32 + n * 16 + lr;
#pragma unroll
                for (int r = 0; r < 4; ++r) {
                    const size_t o = (size_t)(row + r) * NDIM + col;
                    Fout[o] = tanh_fast(acc[m][n][r] + U[o]);
                }
            }
        }
    } else if (MODE == 2) {
        ushortT* Fout = (ushortT*)FoutV;
#pragma unroll
        for (int m = 0; m < 2; ++m) {
            const int row = bm * 64 + wr * 32 + m * 16 + r0;
#pragma unroll
            for (int n = 0; n < 2; ++n) {
                const int col = bn * 64 + wc * 32 + n * 16 + lr;
#pragma unroll
                for (int r = 0; r < 4; ++r) {
                    const size_t o = (size_t)(row + r) * NDIM + col;
                    const float f = tanh_fast(acc[m][n][r] + U[o]);
                    Fout[o] = f2bf(f);
                    G[(size_t)s * NTOT + o] = f2bf(f - Xcur[o]);
                }
            }
        }
    } else {  // MODE 1: Hutchinson accumulate
        float psum = 0.f;
#pragma unroll
        for (int m = 0; m < 2; ++m) {
            const int row = bm * 64 + wr * 32 + m * 16 + r0;
#pragma unroll
            for (int n = 0; n < 2; ++n) {
                const int col = bn * 64 + wc * 32 + n * 16 + lr;
#pragma unroll
                for (int r = 0; r < 4; ++r) {
                    const size_t o = (size_t)(row + r) * NDIM + col;
                    const float t = xstar[o];
                    const float tang = (1.f - t * t) * acc[m][n][r];
                    psum += tang * tang;
                }
            }
        }
#pragma unroll
        for (int off = 32; off > 0; off >>= 1) psum += __shfl_down(psum, off);
        __syncthreads();
        float* red = (float*)lA;
        if (lane == 0) red[w] = psum;
        __syncthreads();
        if (tid == 0)
            atomicAdd(jac, (red[0] + red[1] + red[2] + red[3]) * (1.0f / (float)NTOT));
    }
}

// ---------------- dots on bf16 residuals: row/col s of gram: <g_s, g_j> for j < cnt
__global__ void k_dotsG(const ushortT* __restrict__ G, float* dots, int s, int cnt) {
    float d[5] = {0.f, 0.f, 0.f, 0.f, 0.f};
    const int stride = gridDim.x * blockDim.x;
    const ushort4* G4 = (const ushort4*)G;
    for (int i = blockIdx.x * blockDim.x + threadIdx.x; i < N8; i += stride) {
        ushort4 s0 = G4[(size_t)s * (NTOT / 4) + 2 * i];
        ushort4 s1 = G4[(size_t)s * (NTOT / 4) + 2 * i + 1];
        float gs[8] = {bf2f(s0.x), bf2f(s0.y), bf2f(s0.z), bf2f(s0.w),
                       bf2f(s1.x), bf2f(s1.y), bf2f(s1.z), bf2f(s1.w)};
#pragma unroll
        for (int j = 0; j < 5; ++j)
            if (j < cnt) {
                if (j == s) {
#pragma unroll
                    for (int e = 0; e < 8; ++e) d[j] += gs[e] * gs[e];
                } else {
                    ushort4 a0 = G4[(size_t)j * (NTOT / 4) + 2 * i];
                    ushort4 a1 = G4[(size_t)j * (NTOT / 4) + 2 * i + 1];
                    d[j] += gs[0] * bf2f(a0.x) + gs[1] * bf2f(a0.y) +
                            gs[2] * bf2f(a0.z) + gs[3] * bf2f(a0.w) +
                            gs[4] * bf2f(a1.x) + gs[5] * bf2f(a1.y) +
                            gs[6] * bf2f(a1.z) + gs[7] * bf2f(a1.w);
                }
            }
    }
    const int w = threadIdx.x >> 6, lane = threadIdx.x & 63;
    __shared__ float red[4][5];
#pragma unroll
    for (int j = 0; j < 5; ++j) {
        float v = d[j];
#pragma unroll
        for (int off = 32; off > 0; off >>= 1) v += __shfl_down(v, off);
        if (lane == 0) red[w][j] = v;
    }
    __syncthreads();
    if (threadIdx.x < 5 && (int)threadIdx.x < cnt) {
        const int j = threadIdx.x;
        const float v = red[0][j] + red[1][j] + red[2][j] + red[3][j];
        atomicAdd(&dots[s * 5 + j], v);
        if (j != s) atomicAdd(&dots[j * 5 + s], v);
    }
}

// ---------------- mix: per-block redundant alpha solve; Xcur(f32) = sum a_j F_j(bf16);
//                  Abf = bf16(Xcur); finisher zeroes dots row/col s for next accumulation
__global__ void k_mix(const ushortT* __restrict__ F, float* __restrict__ dots,
                      float* __restrict__ Xcur, ushortT* __restrict__ Abf,
                      int nk, int s) {
    __shared__ float sa[5];
    if (threadIdx.x == 0) solve5(dots, sa, nk);
    __syncthreads();
    float a[5];
#pragma unroll
    for (int i = 0; i < 5; ++i) a[i] = sa[i];

    const int stride = gridDim.x * blockDim.x;
    const ushort4* F4 = (const ushort4*)F;
    for (int i = blockIdx.x * blockDim.x + threadIdx.x; i < N8; i += stride) {
        float sv[8] = {0.f, 0.f, 0.f, 0.f, 0.f, 0.f, 0.f, 0.f};
#pragma unroll
        for (int j = 0; j < 5; ++j)
            if (j < nk) {
                const ushort4 f0 = F4[(size_t)j * (NTOT / 4) + 2 * i];
                const ushort4 f1 = F4[(size_t)j * (NTOT / 4) + 2 * i + 1];
                sv[0] += a[j] * bf2f(f0.x); sv[1] += a[j] * bf2f(f0.y);
                sv[2] += a[j] * bf2f(f0.z); sv[3] += a[j] * bf2f(f0.w);
                sv[4] += a[j] * bf2f(f1.x); sv[5] += a[j] * bf2f(f1.y);
                sv[6] += a[j] * bf2f(f1.z); sv[7] += a[j] * bf2f(f1.w);
            }
        ((float4*)Xcur)[2 * i]     = make_float4(sv[0], sv[1], sv[2], sv[3]);
        ((float4*)Xcur)[2 * i + 1] = make_float4(sv[4], sv[5], sv[6], sv[7]);
        ushort4 p0, p1;
        p0.x = f2bf(sv[0]); p0.y = f2bf(sv[1]); p0.z = f2bf(sv[2]); p0.w = f2bf(sv[3]);
        p1.x = f2bf(sv[4]); p1.y = f2bf(sv[5]); p1.z = f2bf(sv[6]); p1.w = f2bf(sv[7]);
        ((ushort4*)Abf)[2 * i]     = p0;
        ((ushort4*)Abf)[2 * i + 1] = p1;
    }
    // finisher: all blocks have read dots (solve5 prologue) before the counter saturates
    if (threadIdx.x == 0) {
        int* counter = (int*)(dots + 31);
        const int old = atomicAdd(counter, 1);
        if (old == (int)gridDim.x - 1) {
#pragma unroll
            for (int j = 0; j < 5; ++j) { dots[s * 5 + j] = 0.f; dots[j * 5 + s] = 0.f; }
            atomicExch(counter, 0);
        }
    }
}

// ---------------- eps: Rademacher +/-1 in bf16
__global__ void k_eps(ushortT* __restrict__ E) {
    const int stride = gridDim.x * blockDim.x;
    for (int i = blockIdx.x * blockDim.x + threadIdx.x; i < N4; i += stride) {
        ushort4 p;
        p.x = (hash_u32(4u * i + 0u) & 1u) ? 0xBF80u : 0x3F80u;
        p.y = (hash_u32(4u * i + 1u) & 1u) ? 0xBF80u : 0x3F80u;
        p.z = (hash_u32(4u * i + 2u) & 1u) ? 0xBF80u : 0x3F80u;
        p.w = (hash_u32(4u * i + 3u) & 1u) ? 0xBF80u : 0x3F80u;
        ((ushort4*)E)[i] = p;
    }
}

extern "C" void kernel_launch(void* const* d_in, const int* in_sizes, int n_in,
                              void* d_out, int out_size, void* d_ws, size_t ws_size,
                              hipStream_t stream) {
    const float* W = (const float*)d_in[1];   // d_in[0] = x unused (x0 = zeros)
    const float* U = (const float*)d_in[2];
    float* out = (float*)d_out;

    // ws: WT bf16 8MB | Abf bf16 8MB (reused as eps) | F[5] bf16 40MB | G[5] bf16 40MB | Xcur f32 16MB | dots 32f
    ushortT* WT  = (ushortT*)d_ws;
    ushortT* Abf = WT + (size_t)NTOT;
    ushortT* Fs  = Abf + (size_t)NTOT;
    ushortT* Gs  = Fs + (size_t)5 * NTOT;
    float* Xcur  = (float*)(Gs + (size_t)5 * NTOT);
    float* dots  = Xcur + (size_t)NTOT;

    hipMemsetAsync(dots, 0, 32 * sizeof(float), stream);    // dots + finisher counter
    hipMemsetAsync(out + NTOT, 0, sizeof(float), stream);   // jac accumulator

    k_transpose<<<dim3(64, 64), dim3(32, 8), 0, stream>>>(W, WT);
    k_init<<<1024, 256, 0, stream>>>(U, Fs, Gs, Xcur, Abf, dots);
    // k=1: F1 = tanh(F0 @ W + u); G1 = bf16(F1 - F0); dots row/col 1 (cnt=2)
    k_gemm<2><<<GEMM_BLOCKS, 256, 0, stream>>>(Abf, WT, U, Fs + (size_t)1 * NTOT,
                                               Xcur, Gs, 1, nullptr, nullptr);
    k_dotsG<<<1024, 256, 0, stream>>>(Gs, dots, 1, 2);
    for (int k = 2; k < 19; ++k) {
        const int s = k % 5;
        const int nk = k < 5 ? k : 5;
        const int cnt = (k + 1 < 5) ? (k + 1) : 5;
        k_mix<<<1024, 256, 0, stream>>>(Fs, dots, Xcur, Abf, nk, s);
        k_gemm<2><<<GEMM_BLOCKS, 256, 0, stream>>>(Abf, WT, U, Fs + (size_t)s * NTOT,
                                                   Xcur, Gs, s, nullptr, nullptr);
        k_dotsG<<<1024, 256, 0, stream>>>(Gs, dots, s, cnt);
    }
    // k = 19: final iterate straight to d_out in f32 (no dots / no F slot needed)
    k_mix<<<1024, 256, 0, stream>>>(Fs, dots, Xcur, Abf, 5, 4);
    k_gemm<0><<<GEMM_BLOCKS, 256, 0, stream>>>(Abf, WT, U, out, nullptr, nullptr, 0,
                                               nullptr, nullptr);
    // jac_reg: independent Rademacher Hutchinson probe
    k_eps<<<1024, 256, 0, stream>>>(Abf);
    k_gemm<1><<<GEMM_BLOCKS, 256, 0, stream>>>(Abf, WT, nullptr, nullptr, nullptr, nullptr, 0,
                                               out, out + NTOT);
}